// Round 1
// baseline (686.150 us; speedup 1.0000x reference)
//
#include <hip/hip_runtime.h>
#include <hip/hip_bf16.h>

// Problem constants
#define M_VIEWS 6
#define N_ROWS  2048
#define D_IN    1152
#define D_HID   128
#define D_K     64
#define TOT_ROWS (M_VIEWS * N_ROWS)   // 12288

typedef short bf16x8 __attribute__((ext_vector_type(8)));
typedef float f32x4  __attribute__((ext_vector_type(4)));

// ---------------------------------------------------------------------------
// Kernel 1: x = x_all @ W + b   (fp32)
// One block = 8 rows, 256 threads. x_all rows staged in LDS (36 KB),
// thread j in group g computes x[row g*4+r][j] for r=0..3.
// ---------------------------------------------------------------------------
__global__ __launch_bounds__(256) void xgemm_kernel(
    const float* __restrict__ xall,  // [12288][1152]
    const float* __restrict__ W,     // [1152][128]
    const float* __restrict__ bias,  // [128]
    float* __restrict__ x)           // [12288][128]
{
    __shared__ float xl[8 * D_IN];
    const int row0 = blockIdx.x * 8;

    // cooperative float4 load of 8 rows
    const float4* src = reinterpret_cast<const float4*>(xall + (size_t)row0 * D_IN);
    float4* dst = reinterpret_cast<float4*>(xl);
    for (int i = threadIdx.x; i < 8 * D_IN / 4; i += 256)
        dst[i] = src[i];
    __syncthreads();

    const int j = threadIdx.x & 127;
    const int g = threadIdx.x >> 7;   // 0 or 1

    float acc[4] = {0.f, 0.f, 0.f, 0.f};
    for (int d = 0; d < D_IN; ++d) {
        float w = W[d * D_HID + j];
        #pragma unroll
        for (int r = 0; r < 4; ++r)
            acc[r] += xl[(g * 4 + r) * D_IN + d] * w;
    }
    float bj = bias[j];
    #pragma unroll
    for (int r = 0; r < 4; ++r)
        x[(size_t)(row0 + g * 4 + r) * D_HID + j] = acc[r] + bj;
}

// ---------------------------------------------------------------------------
// Kernel 2: retrieve — E[mat][row] = P @ softmax(x[row] @ P), cast to bf16.
// One wave per row (4 rows / block of 256).
// ---------------------------------------------------------------------------
__global__ __launch_bounds__(256) void retrieve_kernel(
    const float* __restrict__ x,     // [12288][128]
    const float* __restrict__ U,     // [128][64]
    const float* __restrict__ V,     // [128][64]
    __hip_bfloat16* __restrict__ E)  // [2][12288][128]
{
    const int w    = threadIdx.x >> 6;
    const int lane = threadIdx.x & 63;
    const int row  = blockIdx.x * 4 + w;

    __shared__ float xs[4][D_HID];
    __shared__ float attns[4][D_K];

    float2 xv = reinterpret_cast<const float2*>(x + (size_t)row * D_HID)[lane];
    xs[w][2 * lane]     = xv.x;
    xs[w][2 * lane + 1] = xv.y;
    __syncthreads();

    #pragma unroll
    for (int mat = 0; mat < 2; ++mat) {
        const float* P = mat ? V : U;

        // logits[lane] = sum_d x[d] * P[d][lane]   (beta = 1)
        float lg = 0.f;
        for (int d = 0; d < D_HID; ++d)
            lg += xs[w][d] * P[d * D_K + lane];

        // softmax over the 64 lanes
        float mx = lg;
        #pragma unroll
        for (int s = 1; s < 64; s <<= 1) mx = fmaxf(mx, __shfl_xor(mx, s));
        float e = __expf(lg - mx);
        float sm = e;
        #pragma unroll
        for (int s = 1; s < 64; s <<= 1) sm += __shfl_xor(sm, s);
        float attn = e / sm;
        attns[w][lane] = attn;
        __syncthreads();

        // E[row][d] = sum_k attn[k] * P[d][k];  lane owns d0=2*lane, d0+1
        float o0 = 0.f, o1 = 0.f;
        const int d0 = 2 * lane;
        for (int kk = 0; kk < D_K; ++kk) {
            float a = attns[w][kk];
            o0 += a * P[d0 * D_K + kk];
            o1 += a * P[(d0 + 1) * D_K + kk];
        }
        __hip_bfloat16* Er = E + ((size_t)mat * TOT_ROWS + row) * D_HID;
        Er[d0]     = __float2bfloat16(o0);
        Er[d0 + 1] = __float2bfloat16(o1);
        __syncthreads();
    }
}

// ---------------------------------------------------------------------------
// Kernel 3: pair LSE. Block = (job, q-tile of 64 rows). 4 waves x 16 rows.
// S = E[m] @ E[k]^T / tau computed via mfma_f32_16x16x32_bf16 with online
// diag-excluded row-logsumexp. Accumulates sum of (lse - pos) into d_out.
// ---------------------------------------------------------------------------
__global__ __launch_bounds__(256) void pair_lse_kernel(
    const __hip_bfloat16* __restrict__ E,  // [2][6][2048][128]
    float* __restrict__ out, float scale)
{
    const int blk = blockIdx.x;      // 60 jobs * 32 qtiles
    const int qt  = blk & 31;
    const int job = blk >> 5;        // 0..59
    const int mat = job / 30;
    const int pr  = job % 30;
    const int m   = pr / 5;
    int k = pr % 5; k += (k >= m);

    const __hip_bfloat16* Qm = E + ((size_t)mat * M_VIEWS + m) * N_ROWS * D_HID;
    const __hip_bfloat16* Kk = E + ((size_t)mat * M_VIEWS + k) * N_ROWS * D_HID;

    const int tid  = threadIdx.x;
    const int wave = tid >> 6;
    const int lane = tid & 63;
    const int lr   = lane & 15;   // frag row/col index
    const int lg   = lane >> 4;   // 0..3 (k-block / row-quad)

    const int qrow0 = qt * 64 + wave * 16;

    // hoist A fragments (wave's 16 q-rows, 4 k-steps)
    bf16x8 afrag[4];
    const __hip_bfloat16* qrowp = Qm + (size_t)(qrow0 + lr) * D_HID;
    #pragma unroll
    for (int s = 0; s < 4; ++s)
        afrag[s] = *reinterpret_cast<const bf16x8*>(qrowp + s * 32 + lg * 8);

    float mrun[4], lrun[4], pos[4];
    #pragma unroll
    for (int j = 0; j < 4; ++j) { mrun[j] = -INFINITY; lrun[j] = 0.f; pos[j] = 0.f; }

    const float invtau = 2.0f;  // 1/TAU

    for (int pt = 0; pt < 32; ++pt) {
        // S strip: 16 rows x 64 cols = 4 col-tiles of 16x16
        f32x4 acc[4];
        #pragma unroll
        for (int ct = 0; ct < 4; ++ct) {
            f32x4 a = {0.f, 0.f, 0.f, 0.f};
            const __hip_bfloat16* krowp = Kk + (size_t)(pt * 64 + ct * 16 + lr) * D_HID;
            #pragma unroll
            for (int s = 0; s < 4; ++s) {
                bf16x8 bfrag = *reinterpret_cast<const bf16x8*>(krowp + s * 32 + lg * 8);
                a = __builtin_amdgcn_mfma_f32_16x16x32_bf16(afrag[s], bfrag, a, 0, 0, 0);
            }
            acc[ct] = a;
        }

        // online LSE update, 4 rows per lane (row = lg*4 + j)
        #pragma unroll
        for (int j = 0; j < 4; ++j) {
            const int grow = qrow0 + lg * 4 + j;   // global n of this row
            const int dcol = grow - pt * 64;       // diag col within p-tile
            float v[4];
            float tmax = -INFINITY;
            #pragma unroll
            for (int ct = 0; ct < 4; ++ct) {
                float val = acc[ct][j] * invtau;
                bool isd = (dcol == ct * 16 + lr);
                if (isd) pos[j] = val;
                v[ct] = isd ? -INFINITY : val;
                tmax = fmaxf(tmax, v[ct]);
            }
            #pragma unroll
            for (int s = 1; s < 16; s <<= 1)
                tmax = fmaxf(tmax, __shfl_xor(tmax, s));
            const float newmax = fmaxf(mrun[j], tmax);
            float psum = 0.f;
            #pragma unroll
            for (int ct = 0; ct < 4; ++ct)
                psum += __expf(v[ct] - newmax);     // exp(-inf)=0 covers diag
            #pragma unroll
            for (int s = 1; s < 16; s <<= 1)
                psum += __shfl_xor(psum, s);
            lrun[j] = lrun[j] * __expf(mrun[j] - newmax) + psum;
            mrun[j] = newmax;
        }
    }

    // finalize: one contribution per row, from lane lr==0 of each 16-group
    float contrib = 0.f;
    #pragma unroll
    for (int j = 0; j < 4; ++j) {
        float p = pos[j];
        #pragma unroll
        for (int s = 1; s < 16; s <<= 1) p += __shfl_xor(p, s);
        float lse = mrun[j] + __logf(lrun[j]);
        if (lr == 0) contrib += (lse - p);
    }
    #pragma unroll
    for (int s = 1; s < 64; s <<= 1) contrib += __shfl_xor(contrib, s);

    __shared__ float bsum[4];
    if (lane == 0) bsum[wave] = contrib;
    __syncthreads();
    if (tid == 0)
        atomicAdd(out, (bsum[0] + bsum[1] + bsum[2] + bsum[3]) * scale);
}

// ---------------------------------------------------------------------------
extern "C" void kernel_launch(void* const* d_in, const int* in_sizes, int n_in,
                              void* d_out, int out_size, void* d_ws, size_t ws_size,
                              hipStream_t stream) {
    const float* xall = (const float*)d_in[0];
    const float* W    = (const float*)d_in[1];
    const float* b    = (const float*)d_in[2];
    const float* U    = (const float*)d_in[3];
    const float* V    = (const float*)d_in[4];
    float* out = (float*)d_out;

    float* x = (float*)d_ws;                                      // 12288*128 f32 = 6.29 MB
    __hip_bfloat16* E = (__hip_bfloat16*)((char*)d_ws + (size_t)TOT_ROWS * D_HID * 4);
    // E: 2 * 12288 * 128 bf16 = 6.29 MB  (total ws use ~12.6 MB)

    hipMemsetAsync(d_out, 0, sizeof(float), stream);

    xgemm_kernel<<<TOT_ROWS / 8, 256, 0, stream>>>(xall, W, b, x);
    retrieve_kernel<<<TOT_ROWS / 4, 256, 0, stream>>>(x, U, V, E);

    const float scale = 1.0f / ((float)N_ROWS * 60.0f);
    pair_lse_kernel<<<60 * 32, 256, 0, stream>>>(E, out, scale);
}